// Round 13
// baseline (13.054 us; speedup 1.0000x reference)
//
#include <hip/hip_runtime.h>

// ParallelLatticeModel v13: v12 + barrier-free 2-tile loop per block.
// 256 blocks x 1024 threads (16 waves); each wave owns one 16-row M-tile per
// tile iteration (2 iterations = 512 rows/block). Staging runs ONCE per block
// (256 stagings vs v12's 512), x is prefetched one tile ahead, and tiles are
// separated only by wave-local lgkmcnt fences (sW is wave-private), so the
// 16 waves desync across the loop and hide each other's latency heads.
// Body per wave per tile is byte-identical to v8/v12 (test-verified layouts).
//
// B=131072 rows, D=16 features, 4 lattices x 4 dims (16 corners), E=24 cols,
// K=16 calibration keypoints.
// C layout: col=lane&15, row=4*(lane>>4)+reg (verified v3-v12).

typedef _Float16 f16x4 __attribute__((ext_vector_type(4)));
typedef float f32x4 __attribute__((ext_vector_type(4)));
typedef float f32x2 __attribute__((ext_vector_type(2)));

namespace {
constexpr int kD = 16, kE = 24, kK = 16, kNV = 16;
constexpr int kThreads = 1024;       // 16 waves
constexpr int kWaves = 16;
constexpr int kRPT = 256;            // rows per tile (16 waves x 16 rows)
constexpr int kTPB = 2;              // tiles per block -> 512 rows/block
constexpr int kKpS  = 17;            // sKp row stride (floats)  - odd pad
constexpr int kAffS = 17;            // sAff row stride (f32x2)  - odd pad
constexpr int kWS   = 67;            // sW region stride (f16x4) - odd pad
constexpr int kK2S  = 20;            // sK2 row stride (floats)  - 16B aligned
}

static __device__ __forceinline__ f32x2 fma2(f32x2 a, f32x2 b, f32x2 c) {
#if __has_builtin(__builtin_elementwise_fma)
    return __builtin_elementwise_fma(a, b, c);
#else
    return (f32x2){fmaf(a[0], b[0], c[0]), fmaf(a[1], b[1], c[1])};
#endif
}
static __device__ __forceinline__ f32x2 fma2s(f32x2 a, float b, float c) {
    return fma2(a, (f32x2){b, b}, (f32x2){c, c});
}
static __device__ __forceinline__ f32x2 clamp01(f32x2 v) {
#if __has_builtin(__builtin_elementwise_max) && __has_builtin(__builtin_elementwise_min)
    return __builtin_elementwise_min(
        __builtin_elementwise_max(v, (f32x2){0.f, 0.f}), (f32x2){1.f, 1.f});
#else
    return (f32x2){fminf(fmaxf(v[0], 0.f), 1.f), fminf(fmaxf(v[1], 0.f), 1.f)};
#endif
}

__global__ __launch_bounds__(kThreads, 8) void lattice_fwd(
    const float* __restrict__ x,
    const float* __restrict__ cal_kp,    // [D][K]
    const float* __restrict__ cal_vals,  // [D][K]
    const float* __restrict__ k1,        // [E][4][16]
    const float* __restrict__ k2,        // [E][16]
    float* __restrict__ out)             // [B][E]
{
    __shared__ float sKp[kD * kKpS];         // padded kp rows, +INF      1.1KB
    __shared__ f32x2 sAff[kD * kAffS];       // {slope, intercept} padded 2.1KB
    __shared__ f16x4 sW[kWaves * 4 * kWS];   // [wave*lattice pad][lane] 33.5KB
    __shared__ f16x4 sK1[4 * 2 * 64];        // [lattice][ntile][lane]    4 KB
    __shared__ float sK2[32 * kK2S];         // [e][j4]{A,B,dA,dB}        2.5KB

    const int tid  = threadIdx.x;
    const int lane = tid & 63;
    const int wv   = __builtin_amdgcn_readfirstlane(tid >> 6);   // 0..15
    const int q    = lane >> 4;          // feature-quarter / lattice
    const int r15  = lane & 15;          // row in tile (ph1) / col e (ph2)

    const int rowTile0 = blockIdx.x * (kRPT * kTPB);

    // coalesced x prefetch for tile 0 (wave covers 16 rows, 1KB contiguous)
    f32x4 xin = *reinterpret_cast<const f32x4*>(
        x + (size_t)(rowTile0 + wv * 16 + r15) * kD + 4 * q);

    // ---------------- phase 0: stage tables (once per block) ----------------
    if (tid < kD * 16) {   // kp search rows (padded): +INF sentinel at k=15
        int d = tid >> 4, k = tid & 15;
        sKp[d * kKpS + k] = (k == 15) ? __builtin_inff() : cal_kp[tid];
    }
    if (tid < kD * 15) {   // affine entries {slope, intercept}
        int d = tid / 15;
        int k = tid - d * 15;
        float kp0 = cal_kp[d * kK + k];
        float kp1 = cal_kp[d * kK + k + 1];
        float v0  = cal_vals[d * kK + k];
        float v1  = cal_vals[d * kK + k + 1];
        float dxv = kp1 - kp0;
        float slope = (dxv > 0.0f) ? (v1 - v0) / dxv : 0.0f;
        sAff[d * kAffS + k] = (f32x2){slope, fmaf(-slope, kp0, v0)};
    }
    if (tid < 512) {   // k1 B-frags: lane ls holds B[k=4*(ls>>4)+j][col=16n+(ls&15)]
        int s  = tid;
        int l  = s >> 7;
        int n  = (s >> 6) & 1;
        int ls = s & 63;
        int e  = n * 16 + (ls & 15);
        int g  = ls >> 4;
        f16x4 v = {(_Float16)0.f, (_Float16)0.f, (_Float16)0.f, (_Float16)0.f};
        if (e < kE) {
            const float* src = k1 + ((size_t)(e * 4 + l) * kNV + 4 * g);
            v[0] = (_Float16)src[0]; v[1] = (_Float16)src[1];
            v[2] = (_Float16)src[2]; v[3] = (_Float16)src[3];
        }
        sK1[s] = v;
    }
    if (tid < 256) {   // k2 per-(e,j4) packs {A,B,dA,dB}
        int e = tid >> 3, j4 = (tid >> 1) & 3, h = tid & 1;
        float a = 0.f, d = 0.f;
        if (e < kE) {
            a = k2[e * kNV + 4 * j4 + 2 * h];
            d = k2[e * kNV + 4 * j4 + 2 * h + 1] - a;
        }
        sK2[e * kK2S + 4 * j4 + h]     = a;
        sK2[e * kK2S + 4 * j4 + 2 + h] = d;
    }

    __syncthreads();   // the ONLY block-wide barrier

    // ---------------- barrier-free tile loop ----------------
    #pragma unroll
    for (int t = 0; t < kTPB; ++t) {
        const int rowBase = rowTile0 + t * kRPT + wv * 16;
        f32x4 xcur = xin;
        if (t + 1 < kTPB)   // prefetch next tile's x (hides under this body)
            xin = *reinterpret_cast<const f32x4*>(
                x + (size_t)(rowTile0 + (t + 1) * kRPT + wv * 16 + r15) * kD + 4 * q);

        // ------- phase 1: calibrate features 4q..4q+3 of row r15 -------
        float xc[4];
        #pragma unroll
        for (int i = 0; i < 4; ++i) {
            const int d = 4 * q + i;
            const float xv = xcur[i];
            const float* kpb = &sKp[d * kKpS];
            int j = 0;
            #pragma unroll
            for (int s = 8; s >= 1; s >>= 1) {    // 4x: b32 read + cmp + cndmask
                float kps = kpb[j + s];
                j = (xv >= kps) ? j + s : j;
            }
            f32x2 ent = sAff[d * kAffS + j];      // {slope, intercept}
            xc[i] = fminf(fmaxf(fmaf(ent[0], xv, ent[1]), 0.0f), 1.0f);
        }

        // multilinear corner weights for lattice q (dim0 = MSB)
        float wf[16];
        {
            float a = xc[0], b = xc[1], c = xc[2], d = xc[3];
            float t2[2] = {1.0f - a, a};
            float t4[4];
            #pragma unroll
            for (int j = 0; j < 2; ++j) { t4[2*j] = t2[j]*(1.0f-b); t4[2*j+1] = t2[j]*b; }
            float t8[8];
            #pragma unroll
            for (int j = 0; j < 4; ++j) { t8[2*j] = t4[j]*(1.0f-c); t8[2*j+1] = t4[j]*c; }
            #pragma unroll
            for (int j = 0; j < 8; ++j) { wf[2*j] = t8[j]*(1.0f-d); wf[2*j+1] = t8[j]*d; }
        }

        // A-frags into the wave's OWN padded region (wave-private; in-order
        // wave LDS ops + lgkmcnt fence make the cross-tile reuse race-free)
        #pragma unroll
        for (int g = 0; g < 4; ++g) {
            f16x4 v;
            v[0] = (_Float16)wf[4*g+0]; v[1] = (_Float16)wf[4*g+1];
            v[2] = (_Float16)wf[4*g+2]; v[3] = (_Float16)wf[4*g+3];
            sW[(wv * 4 + q) * kWS + r15 + 16 * g] = v;
        }
        asm volatile("s_waitcnt lgkmcnt(0)" ::: "memory");   // wave-local fence

        f16x4 af[4];
        #pragma unroll
        for (int l = 0; l < 4; ++l) af[l] = sW[(wv * 4 + l) * kWS + lane];

        // ------- phase 2: MFMA layer-1 + packed layer-2 -------
        #pragma unroll
        for (int n = 0; n < 2; ++n) {
            const int e = n * 16 + r15;

            f32x4 acc[4];
            #pragma unroll
            for (int l = 0; l < 4; ++l) {
                f16x4 bf = sK1[(l * 2 + n) * 64 + lane];
                acc[l] = __builtin_amdgcn_mfma_f32_16x16x16f16(
                    af[l], bf, (f32x4){0.f, 0.f, 0.f, 0.f}, 0, 0, 0);
            }

            // h3/h2 for both row-pairs (p=0: rows 4q+0,1; p=1: rows 4q+2,3)
            f32x2 h3a = clamp01((f32x2){acc[3][0], acc[3][1]});
            f32x2 h3b = clamp01((f32x2){acc[3][2], acc[3][3]});
            f32x2 h2a = clamp01((f32x2){acc[2][0], acc[2][1]});
            f32x2 h2b = clamp01((f32x2){acc[2][2], acc[2][3]});

            f32x2 v4a[4], v4b[4];
            const float* kr = &sK2[e * kK2S];
            #pragma unroll
            for (int j4 = 0; j4 < 4; ++j4) {
                f32x4 kq = *reinterpret_cast<const f32x4*>(kr + 4 * j4); // {A,B,dA,dB}
                f32x2 a0 = fma2s(h3a, kq[2], kq[0]);
                f32x2 b0 = fma2s(h3a, kq[3], kq[1]);
                v4a[j4]  = fma2(h2a, b0 - a0, a0);
                f32x2 a1 = fma2s(h3b, kq[2], kq[0]);
                f32x2 b1 = fma2s(h3b, kq[3], kq[1]);
                v4b[j4]  = fma2(h2b, b1 - a1, a1);
            }

            #pragma unroll
            for (int p = 0; p < 2; ++p) {
                f32x2 h1 = clamp01((f32x2){acc[1][2*p], acc[1][2*p+1]});
                f32x2 h0 = clamp01((f32x2){acc[0][2*p], acc[0][2*p+1]});
                const f32x2* v4 = (p == 0) ? v4a : v4b;   // compile-time select
                f32x2 w0 = fma2(h1, v4[1] - v4[0], v4[0]);
                f32x2 w1 = fma2(h1, v4[3] - v4[2], v4[2]);
                f32x2 o  = fma2(h0, w1 - w0, w0);
                if (e < kE) {   // exec-masked store (row=4q+2p(+1), col=e)
                    size_t r0 = (size_t)(rowBase + q * 4 + 2 * p);
                    out[r0 * kE + e]       = o[0];
                    out[(r0 + 1) * kE + e] = o[1];
                }
            }
        }
    }
}

extern "C" void kernel_launch(void* const* d_in, const int* in_sizes, int n_in,
                              void* d_out, int out_size, void* d_ws, size_t ws_size,
                              hipStream_t stream) {
    const float* x        = (const float*)d_in[0];
    const float* cal_kp   = (const float*)d_in[1];
    const float* cal_vals = (const float*)d_in[2];
    const float* k1       = (const float*)d_in[3];
    const float* k2       = (const float*)d_in[4];
    float* out = (float*)d_out;

    hipLaunchKernelGGL(lattice_fwd, dim3(131072 / (kRPT * kTPB)), dim3(kThreads),
                       0, stream, x, cal_kp, cal_vals, k1, k2, out);
}

// Round 15
// 12.947 us; speedup vs baseline: 1.0083x; 1.0083x over previous
//
#include <hip/hip_runtime.h>

// ParallelLatticeModel v14b: v14 with the cvt_pkrtz type mismatch fixed
// (__builtin_amdgcn_cvt_pkrtz returns __fp16x2; element-cast into f16x4).
// Structure identical to v12 (512 blocks x 1024 threads, 16 waves x 16-row
// M-tiles, single staging + single barrier); weight build in packed f32x2
// ops + pkrtz packing. Test-verified layouts v3-v13 unchanged.
//
// B=131072 rows, D=16 features, 4 lattices x 4 dims (16 corners), E=24 cols,
// K=16 calibration keypoints.
// C layout: col=lane&15, row=4*(lane>>4)+reg (verified).

typedef _Float16 f16x4 __attribute__((ext_vector_type(4)));
typedef float f32x4 __attribute__((ext_vector_type(4)));
typedef float f32x2 __attribute__((ext_vector_type(2)));

namespace {
constexpr int kD = 16, kE = 24, kK = 16, kNV = 16;
constexpr int kThreads = 1024;       // 16 waves
constexpr int kWaves = 16;
constexpr int kRPB = 256;            // rows per block (16 waves x 16 rows)
constexpr int kKpS  = 17;            // sKp row stride (floats)  - odd pad
constexpr int kAffS = 17;            // sAff row stride (f32x2)  - odd pad
constexpr int kWS   = 67;            // sW region stride (f16x4) - odd pad
constexpr int kK2S  = 20;            // sK2 row stride (floats)  - 16B aligned
}

static __device__ __forceinline__ f32x2 fma2(f32x2 a, f32x2 b, f32x2 c) {
#if __has_builtin(__builtin_elementwise_fma)
    return __builtin_elementwise_fma(a, b, c);
#else
    return (f32x2){fmaf(a[0], b[0], c[0]), fmaf(a[1], b[1], c[1])};
#endif
}
static __device__ __forceinline__ f32x2 fma2s(f32x2 a, float b, float c) {
    return fma2(a, (f32x2){b, b}, (f32x2){c, c});
}
static __device__ __forceinline__ f32x2 clamp01(f32x2 v) {
#if __has_builtin(__builtin_elementwise_max) && __has_builtin(__builtin_elementwise_min)
    return __builtin_elementwise_min(
        __builtin_elementwise_max(v, (f32x2){0.f, 0.f}), (f32x2){1.f, 1.f});
#else
    return (f32x2){fminf(fmaxf(v[0], 0.f), 1.f), fminf(fmaxf(v[1], 0.f), 1.f)};
#endif
}

__global__ __launch_bounds__(kThreads, 8) void lattice_fwd(
    const float* __restrict__ x,
    const float* __restrict__ cal_kp,    // [D][K]
    const float* __restrict__ cal_vals,  // [D][K]
    const float* __restrict__ k1,        // [E][4][16]
    const float* __restrict__ k2,        // [E][16]
    float* __restrict__ out)             // [B][E]
{
    __shared__ float sKp[kD * kKpS];         // padded kp rows, +INF      1.1KB
    __shared__ f32x2 sAff[kD * kAffS];       // {slope, intercept} padded 2.1KB
    __shared__ f16x4 sW[kWaves * 4 * kWS];   // [wave*lattice pad][lane] 33.5KB
    __shared__ f16x4 sK1[4 * 2 * 64];        // [lattice][ntile][lane]    4 KB
    __shared__ float sK2[32 * kK2S];         // [e][j4]{A,B,dA,dB}        2.5KB

    const int tid  = threadIdx.x;
    const int lane = tid & 63;
    const int wv   = __builtin_amdgcn_readfirstlane(tid >> 6);   // 0..15
    const int q    = lane >> 4;          // feature-quarter / lattice
    const int r15  = lane & 15;          // row in tile (ph1) / col e (ph2)

    const int rowBase = blockIdx.x * kRPB + wv * 16;

    // coalesced x prefetch: wave covers rows rowBase..+15 (1KB contiguous)
    f32x4 xin = *reinterpret_cast<const f32x4*>(
        x + (size_t)(rowBase + r15) * kD + 4 * q);

    // ---------------- phase 0: stage tables (1024 threads, one shot) -------
    if (tid < kD * 16) {   // kp search rows (padded): +INF sentinel at k=15
        int d = tid >> 4, k = tid & 15;
        sKp[d * kKpS + k] = (k == 15) ? __builtin_inff() : cal_kp[tid];
    }
    if (tid < kD * 15) {   // affine entries {slope, intercept}
        int d = tid / 15;
        int k = tid - d * 15;
        float kp0 = cal_kp[d * kK + k];
        float kp1 = cal_kp[d * kK + k + 1];
        float v0  = cal_vals[d * kK + k];
        float v1  = cal_vals[d * kK + k + 1];
        float dxv = kp1 - kp0;
        float slope = (dxv > 0.0f) ? (v1 - v0) / dxv : 0.0f;
        sAff[d * kAffS + k] = (f32x2){slope, fmaf(-slope, kp0, v0)};
    }
    if (tid < 512) {   // k1 B-frags: lane ls holds B[k=4*(ls>>4)+j][col=16n+(ls&15)]
        int s  = tid;
        int l  = s >> 7;
        int n  = (s >> 6) & 1;
        int ls = s & 63;
        int e  = n * 16 + (ls & 15);
        int g  = ls >> 4;
        f16x4 v = {(_Float16)0.f, (_Float16)0.f, (_Float16)0.f, (_Float16)0.f};
        if (e < kE) {
            const float* src = k1 + ((size_t)(e * 4 + l) * kNV + 4 * g);
            v[0] = (_Float16)src[0]; v[1] = (_Float16)src[1];
            v[2] = (_Float16)src[2]; v[3] = (_Float16)src[3];
        }
        sK1[s] = v;
    }
    if (tid < 256) {   // k2 per-(e,j4) packs {A,B,dA,dB}
        int e = tid >> 3, j4 = (tid >> 1) & 3, h = tid & 1;
        float a = 0.f, d = 0.f;
        if (e < kE) {
            a = k2[e * kNV + 4 * j4 + 2 * h];
            d = k2[e * kNV + 4 * j4 + 2 * h + 1] - a;
        }
        sK2[e * kK2S + 4 * j4 + h]     = a;
        sK2[e * kK2S + 4 * j4 + 2 + h] = d;
    }

    __syncthreads();   // the ONLY block-wide barrier

    // ------------- phase 1: calibrate features 4q..4q+3 of row r15 -------------
    float xc[4];
    #pragma unroll
    for (int i = 0; i < 4; ++i) {
        const int d = 4 * q + i;
        const float xv = xin[i];
        const float* kpb = &sKp[d * kKpS];
        int j = 0;
        #pragma unroll
        for (int s = 8; s >= 1; s >>= 1) {        // 4x: b32 read + cmp + cndmask
            float kps = kpb[j + s];
            j = (xv >= kps) ? j + s : j;
        }
        f32x2 ent = sAff[d * kAffS + j];          // {slope, intercept}
        xc[i] = fminf(fmaxf(fmaf(ent[0], xv, ent[1]), 0.0f), 1.0f);
    }

    // -------- multilinear corner weights for lattice q, PACKED build --------
    // corner = 8*b0 + 4*b1 + 2*b2 + b3 (dim0 = MSB). Build as f32x2 pk ops,
    // pack straight to f16 with v_cvt_pkrtz_f16_f32.
    f16x4 afw[4];
    {
        const float a = xc[0], b = xc[1], c = xc[2], d = xc[3];
        const f32x2 tb = {1.0f - b, b};
        const f32x2 tc = {1.0f - c, c};
        const f32x2 td = {1.0f - d, d};
        f32x2 t4lo = (f32x2){1.0f - a, 1.0f - a} * tb;   // {t4[00], t4[01]}
        f32x2 t4hi = (f32x2){a, a} * tb;                 // {t4[10], t4[11]}
        f32x2 t8_0 = (f32x2){t4lo[0], t4lo[0]} * tc;     // {t8[000], t8[001]}
        f32x2 t8_1 = (f32x2){t4lo[1], t4lo[1]} * tc;
        f32x2 t8_2 = (f32x2){t4hi[0], t4hi[0]} * tc;
        f32x2 t8_3 = (f32x2){t4hi[1], t4hi[1]} * tc;
        #pragma unroll
        for (int g = 0; g < 4; ++g) {
            f32x2 t8g = (g == 0) ? t8_0 : (g == 1) ? t8_1 : (g == 2) ? t8_2 : t8_3;
            f32x2 plo = (f32x2){t8g[0], t8g[0]} * td;    // {wf[4g],   wf[4g+1]}
            f32x2 phi = (f32x2){t8g[1], t8g[1]} * td;    // {wf[4g+2], wf[4g+3]}
            auto hlo = __builtin_amdgcn_cvt_pkrtz(plo[0], plo[1]);  // __fp16x2
            auto hhi = __builtin_amdgcn_cvt_pkrtz(phi[0], phi[1]);
            afw[g] = (f16x4){(_Float16)hlo[0], (_Float16)hlo[1],
                             (_Float16)hhi[0], (_Float16)hhi[1]};
        }
    }

    // A-frags into the wave's OWN padded region (wave-private)
    #pragma unroll
    for (int g = 0; g < 4; ++g)
        sW[(wv * 4 + q) * kWS + r15 + 16 * g] = afw[g];
    asm volatile("s_waitcnt lgkmcnt(0)" ::: "memory");   // wave-local fence

    f16x4 af[4];
    #pragma unroll
    for (int l = 0; l < 4; ++l) af[l] = sW[(wv * 4 + l) * kWS + lane];

    // ---------------- phase 2: MFMA layer-1 + packed layer-2 ----------------
    #pragma unroll
    for (int n = 0; n < 2; ++n) {
        const int e = n * 16 + r15;

        f32x4 acc[4];
        #pragma unroll
        for (int l = 0; l < 4; ++l) {
            f16x4 bf = sK1[(l * 2 + n) * 64 + lane];
            acc[l] = __builtin_amdgcn_mfma_f32_16x16x16f16(
                af[l], bf, (f32x4){0.f, 0.f, 0.f, 0.f}, 0, 0, 0);
        }

        // h3/h2 for both row-pairs (p=0: rows 4q+0,1; p=1: rows 4q+2,3)
        f32x2 h3a = clamp01((f32x2){acc[3][0], acc[3][1]});
        f32x2 h3b = clamp01((f32x2){acc[3][2], acc[3][3]});
        f32x2 h2a = clamp01((f32x2){acc[2][0], acc[2][1]});
        f32x2 h2b = clamp01((f32x2){acc[2][2], acc[2][3]});

        f32x2 v4a[4], v4b[4];
        const float* kr = &sK2[e * kK2S];
        #pragma unroll
        for (int j4 = 0; j4 < 4; ++j4) {
            f32x4 kq = *reinterpret_cast<const f32x4*>(kr + 4 * j4); // {A,B,dA,dB}
            f32x2 a0 = fma2s(h3a, kq[2], kq[0]);
            f32x2 b0 = fma2s(h3a, kq[3], kq[1]);
            v4a[j4]  = fma2(h2a, b0 - a0, a0);
            f32x2 a1 = fma2s(h3b, kq[2], kq[0]);
            f32x2 b1 = fma2s(h3b, kq[3], kq[1]);
            v4b[j4]  = fma2(h2b, b1 - a1, a1);
        }

        #pragma unroll
        for (int p = 0; p < 2; ++p) {
            f32x2 h1 = clamp01((f32x2){acc[1][2*p], acc[1][2*p+1]});
            f32x2 h0 = clamp01((f32x2){acc[0][2*p], acc[0][2*p+1]});
            const f32x2* v4 = (p == 0) ? v4a : v4b;   // compile-time select
            f32x2 w0 = fma2(h1, v4[1] - v4[0], v4[0]);
            f32x2 w1 = fma2(h1, v4[3] - v4[2], v4[2]);
            f32x2 o  = fma2(h0, w1 - w0, w0);
            if (e < kE) {   // exec-masked store (C layout: row=4q+2p(+1), col=e)
                size_t r0 = (size_t)(rowBase + q * 4 + 2 * p);
                out[r0 * kE + e]       = o[0];
                out[(r0 + 1) * kE + e] = o[1];
            }
        }
    }
}

extern "C" void kernel_launch(void* const* d_in, const int* in_sizes, int n_in,
                              void* d_out, int out_size, void* d_ws, size_t ws_size,
                              hipStream_t stream) {
    const float* x        = (const float*)d_in[0];
    const float* cal_kp   = (const float*)d_in[1];
    const float* cal_vals = (const float*)d_in[2];
    const float* k1       = (const float*)d_in[3];
    const float* k2       = (const float*)d_in[4];
    float* out = (float*)d_out;

    hipLaunchKernelGGL(lattice_fwd, dim3(131072 / kRPB), dim3(kThreads), 0, stream,
                       x, cal_kp, cal_vals, k1, k2, out);
}